// Round 17
// baseline (328.587 us; speedup 1.0000x reference)
//
#include <hip/hip_runtime.h>
#include <cstddef>
#include <cstdint>

#define BATCH 32
#define SEQ 2048
#define DM 1024

typedef __attribute__((ext_vector_type(8))) _Float16 half8v;
typedef __attribute__((ext_vector_type(4))) _Float16 half4v;
typedef __attribute__((ext_vector_type(2))) __fp16 fp16x2;   // cvt_pkrtz native type
typedef __attribute__((ext_vector_type(4))) float f32x4;

// Persistent device-global scratch (fully rewritten every launch)
// g_Apk: keys fp16 pre-swizzled into the scores-kernel LDS image (128 MB):
//   [mtile 512][kt 16][seg 16][lane 64][e 8], seg = (sub*4+kc)*2 + (row>>6),
//   content = keys[mtile*128+row][kt*64 + sub*32 + kc*8 + e], lane = row&63.
__device__ _Float16 g_Apk[(size_t)512 * 16 * 16 * 64 * 8];
// g_Bpk: Wk_w fp16 in FRAGMENT order [nc 8][sub 8][kt 32][kgrp 4][row 16][e 8] (2 MB).
__device__ _Float16 g_Bpk[8 * 8 * 32 * 4 * 16 * 8];
__device__ float g_q[BATCH * DM];              // q projection (128 KB)
__device__ float g_sp[16][BATCH * SEQ];        // scores partials: slot = nchunk*2 + wn

// tanh(x) = 1 - 2/(e^{2x}+1); saturates to +-1 correctly for |x| large
__device__ __forceinline__ float tanh_fast(float x) {
    float e = __expf(2.0f * x);
    return 1.0f - 2.0f / (e + 1.0f);
}

__device__ __forceinline__ void gload16(const void* g, void* l) {
    __builtin_amdgcn_global_load_lds((__attribute__((address_space(1))) void*)g,
                                     (__attribute__((address_space(3))) void*)l, 16, 0, 0);
}

// ---------------- pack keys -> fp16 LDS-image (once; coalesced both sides) ----------
// Reads: 8x128B contiguous segments/inst. Writes: 4 segs x 128B contiguous/inst.
__global__ __launch_bounds__(256) void packa_kernel(const float* __restrict__ keys) {
    int blk = blockIdx.x;              // 0..8191 = mtile*16 + kt
    int mtile = blk >> 4, kt = blk & 15;
    int t = threadIdx.x;
    int w = t >> 6, l = t & 63;
    int r8 = l >> 3;                   // row within 8-row group
    int cc = l & 7;                    // col chunk (8 floats = one 16B fp16 chunk)
    const float* src = keys + (size_t)(mtile * 128 + w * 32 + r8) * DM + kt * 64 + cc * 8;
    _Float16* dst = g_Apk + (size_t)blk * 8192;
#pragma unroll
    for (int j = 0; j < 4; ++j) {
        int row = w * 32 + r8 + j * 8;
        float4 f0 = *reinterpret_cast<const float4*>(src + (size_t)j * 8 * DM);
        float4 f1 = *reinterpret_cast<const float4*>(src + (size_t)j * 8 * DM + 4);
        union { fp16x2 h2[4]; half8v v; } u;
        u.h2[0] = __builtin_amdgcn_cvt_pkrtz(f0.x, f0.y);
        u.h2[1] = __builtin_amdgcn_cvt_pkrtz(f0.z, f0.w);
        u.h2[2] = __builtin_amdgcn_cvt_pkrtz(f1.x, f1.y);
        u.h2[3] = __builtin_amdgcn_cvt_pkrtz(f1.z, f1.w);
        int seg = cc * 2 + (row >> 6);   // cc = sub*4+kc
        *reinterpret_cast<half8v*>(dst + (size_t)seg * 512 + (row & 63) * 8) = u.v;
    }
}

// ---------------- pack Wk_w -> fp16 fragment-major layout (once, ~4 MB) ----------------
__global__ __launch_bounds__(256) void packb_kernel(const float* __restrict__ Wk_w) {
    int blk = blockIdx.x;              // 0..63 = nc*8 + sub
    int nc = blk >> 3, sub = blk & 7;
    int t = threadIdx.x;
    int row = t & 15, kgrp = (t >> 4) & 3, kt0 = t >> 6;   // kt0: 0..3
    const float* src = Wk_w + (size_t)(nc * 128 + sub * 16 + row) * DM;
    _Float16* dst = g_Bpk + (size_t)blk * 16384;           // block-local [kt][kgrp][row][8]
#pragma unroll
    for (int pass = 0; pass < 8; ++pass) {
        int kt = pass * 4 + kt0;
        float4 w0 = *reinterpret_cast<const float4*>(src + kt * 32 + kgrp * 8);
        float4 w1 = *reinterpret_cast<const float4*>(src + kt * 32 + kgrp * 8 + 4);
        union { _Float16 f[8]; half8v v; } h;
        h.f[0] = (_Float16)w0.x; h.f[1] = (_Float16)w0.y;
        h.f[2] = (_Float16)w0.z; h.f[3] = (_Float16)w0.w;
        h.f[4] = (_Float16)w1.x; h.f[5] = (_Float16)w1.y;
        h.f[6] = (_Float16)w1.z; h.f[7] = (_Float16)w1.w;
        *reinterpret_cast<half8v*>(&dst[(size_t)((kt * 4 + kgrp) * 16 + row) * 8]) = h.v;
    }
}

// ---------------- init: zero context (atomically accumulated) ----------------
__global__ __launch_bounds__(256) void init_kernel(float* __restrict__ context) {
    int idx = blockIdx.x * 256 + threadIdx.x;
    if (idx < BATCH * DM) context[idx] = 0.f;
}

// ---------------- q projection: block per output d; Wq read once total ----------------
__global__ __launch_bounds__(256) void qproj_kernel(const float* __restrict__ query,
                                                    const float* __restrict__ Wq_w,
                                                    const float* __restrict__ Wq_b) {
    int d = blockIdx.x;
    int t = threadIdx.x;
    __shared__ float wrow[DM];
    __shared__ float part[8][32];
    reinterpret_cast<float4*>(wrow)[t] =
        reinterpret_cast<const float4*>(Wq_w + (size_t)d * DM)[t];
    __syncthreads();
    int b = t & 31, seg = t >> 5;
    const float4* qp = reinterpret_cast<const float4*>(query + b * DM + seg * 128);
    const float4* wp = reinterpret_cast<const float4*>(wrow + seg * 128);
    float acc = 0.f;
#pragma unroll
    for (int i = 0; i < 32; ++i) {
        float4 qv = qp[i];
        float4 wv = wp[i];
        acc += qv.x * wv.x + qv.y * wv.y + qv.z * wv.z + qv.w * wv.w;
    }
    part[seg][b] = acc;
    __syncthreads();
    if (t < 32) {
        float s = Wq_b[d];
#pragma unroll
        for (int g = 0; g < 8; ++g) s += part[g][t];
        g_q[t * DM + d] = s;
    }
}

// ---------------- scores: pure-fp16 MFMA GEMM; A via DMA, B from L2 ----------
#define BM 128
#define BN 128
#define NT2 16   // 16 K-tiles of 64

// (256,3): 170-reg budget; ~128 used + headroom (no forced accvgpr shuffles).
__global__ __launch_bounds__(256, 3) void scores_kernel(const float* __restrict__ Wk_b,
                                                        const float* __restrict__ v_w) {
    // A image: [dbuf][16 seg x 520 halfs]; seg stride 520 halfs; DMA dest linear.
    __shared__ _Float16 AhS[2][16 * 520];   // 33,280 B

    // XCD-aware order: 4096 blocks = 8 XCDs x 512 slots (bijective); nchunk-minor.
    const unsigned bid = blockIdx.x;
    const unsigned L = (bid & 7u) * 512u + (bid >> 3);
    const int mtile = (int)(L >> 3);       // 0..511
    const int nchunk = (int)(L & 7u);      // 0..7
    const int m0 = mtile * BM;
    const int n0 = nchunk * BN;
    const int b = m0 >> 11;

    const int t = threadIdx.x;
    const int w = t >> 6, l = t & 63;
    const int wm = w >> 1, wn = w & 1;     // 2x2 waves; wave tile 64m x 64n
    const int lr = l & 15, lg = l >> 4;

    // A-frag base (halfs): seg = sub*8 + lg*2 + wm; row-in-seg = mi*16+lr
    const int abase = (lg * 2 + wm) * 520 + lr * 8;   // + sub*4160 + mi*128

    // B-frag base: lane l -> contiguous 16B of frag (kgrp=l>>4, row=l&15).
    const _Float16* Bp = g_Bpk + ((size_t)(nchunk * 8 + wn * 4)) * 16384
                               + (size_t)(l >> 4) * 128 + (size_t)(l & 15) * 8;

    half8v bE[4], bO[4];     // B-frags: bE = sub0, bO = sub1 (named: rule #20)

    f32x4 acc[4][4];
#pragma unroll
    for (int mi = 0; mi < 4; ++mi)
#pragma unroll
        for (int ni = 0; ni < 4; ++ni)
#pragma unroll
            for (int c = 0; c < 4; ++c) acc[mi][ni][c] = 0.f;

    // wave w DMAs segments w*4..w*4+3 (each: 64 lanes x 16B, linear dest)
#define ISSUE_A(kt, bufi)                                                        \
    {                                                                            \
        const _Float16* ga = g_Apk + ((size_t)(mtile * 16 + (kt))) * 8192        \
                           + (size_t)(w * 4) * 512 + (size_t)l * 8;              \
        _Pragma("unroll") for (int i = 0; i < 4; ++i)                            \
            gload16(ga + i * 512, &AhS[bufi][(w * 4 + i) * 520]);                \
    }
#define LOAD_BF(ks, dst)                                                         \
    {                                                                            \
        _Pragma("unroll") for (int ni = 0; ni < 4; ++ni)                         \
            dst[ni] = *reinterpret_cast<const half8v*>(                          \
                Bp + (size_t)ni * 16384 + (size_t)(ks) * 512);                   \
    }
#define COMPUTE_S(bufi, sub, breg)                                               \
    {                                                                            \
        __builtin_amdgcn_s_setprio(1);                                           \
        _Pragma("unroll") for (int mi = 0; mi < 4; ++mi) {                       \
            half8v ahv = *reinterpret_cast<const half8v*>(                       \
                &AhS[bufi][abase + (sub) * 4160 + mi * 128]);                    \
            _Pragma("unroll") for (int ni = 0; ni < 4; ++ni)                     \
                acc[mi][ni] = __builtin_amdgcn_mfma_f32_16x16x32_f16(            \
                    ahv, breg[ni], acc[mi][ni], 0, 0, 0);                        \
        }                                                                        \
        __builtin_amdgcn_s_setprio(0);                                          \
    }

    // ---- prologue: B(0) first (older in FIFO), then A(0) DMA; drain both ----
    LOAD_BF(0, bE);
    ISSUE_A(0, 0);
    asm volatile("s_waitcnt vmcnt(0)" ::: "memory");
    __builtin_amdgcn_s_barrier();
    asm volatile("" ::: "memory");

    // ---- main loop (r15-proven schedule). A(tt+1) DMA is issued at the TOP and
    // is DRAINED BY THE PRE-BARRIER vmcnt(4) (producer-side: global_load_lds
    // writes LDS that OTHER waves read; per-wave vmcnt on the consumer side
    // cannot order that -> r16's NaN race). Only bE(tt+1), the 4 newest loads,
    // rides through the barrier (register dest: scoreboard handles its use).
    for (int tt = 0; tt < NT2; ++tt) {
        const int cb = tt & 1;
        if (tt + 1 < NT2) ISSUE_A(tt + 1, cb ^ 1);
        LOAD_BF(2 * tt + 1, bO);
        COMPUTE_S(cb, 0, bE);
        if (tt + 1 < NT2) LOAD_BF(2 * tt + 2, bE);
        COMPUTE_S(cb, 1, bO);
        asm volatile("s_waitcnt vmcnt(4)" ::: "memory");
        __builtin_amdgcn_s_barrier();
        asm volatile("" ::: "memory");
    }

    // epilogue: tanh * v_w, reduce over this wave's 64 n-cols.
    // Slot = nchunk*2 + wn: exactly ONE writer per (slot,row) -> deterministic.
    float qb[4], vw[4];
#pragma unroll
    for (int ni = 0; ni < 4; ++ni) {
        int n = n0 + wn * 64 + ni * 16 + lr;
        qb[ni] = g_q[b * DM + n] + Wk_b[n];
        vw[ni] = v_w[n];
    }
#pragma unroll
    for (int mi = 0; mi < 4; ++mi) {
#pragma unroll
        for (int rg = 0; rg < 4; ++rg) {
            float p = 0.f;
#pragma unroll
            for (int ni = 0; ni < 4; ++ni) {
                float val = acc[mi][ni][rg] + qb[ni];
                p += tanh_fast(val) * vw[ni];
            }
#pragma unroll
            for (int off = 8; off >= 1; off >>= 1) p += __shfl_xor(p, off, 16);
            if (lr == 0)
                g_sp[nchunk * 2 + wn][m0 + wm * 64 + mi * 16 + lg * 4 + rg] = p;
        }
    }
#undef ISSUE_A
#undef LOAD_BF
#undef COMPUTE_S
}

// ---------------- softmax over S per batch row (sums the 16 partial slots) --------
__global__ __launch_bounds__(256) void softmax_kernel(float* __restrict__ attn) {
    int b = blockIdx.x;
    int tid = threadIdx.x;
    __shared__ float redm[4];
    __shared__ float reds[4];
    float v[8];
    float mx = -1e30f;
#pragma unroll
    for (int i = 0; i < 8; ++i) {
        int idx = b * SEQ + i * 256 + tid;
        float s = 0.f;
#pragma unroll
        for (int pslot = 0; pslot < 16; ++pslot) s += g_sp[pslot][idx];
        v[i] = s;
        mx = fmaxf(mx, v[i]);
    }
#pragma unroll
    for (int off = 32; off >= 1; off >>= 1) mx = fmaxf(mx, __shfl_xor(mx, off));
    int wid = tid >> 6;
    if ((tid & 63) == 0) redm[wid] = mx;
    __syncthreads();
    mx = fmaxf(fmaxf(redm[0], redm[1]), fmaxf(redm[2], redm[3]));
    float sum = 0.f;
#pragma unroll
    for (int i = 0; i < 8; ++i) {
        v[i] = expf(v[i] - mx);
        sum += v[i];
    }
#pragma unroll
    for (int off = 32; off >= 1; off >>= 1) sum += __shfl_xor(sum, off);
    if ((tid & 63) == 0) reds[wid] = sum;
    __syncthreads();
    sum = reds[0] + reds[1] + reds[2] + reds[3];
    float inv = 1.f / sum;
#pragma unroll
    for (int i = 0; i < 8; ++i) attn[b * SEQ + i * 256 + tid] = v[i] * inv;
}

// ---------------- context = attn @ keys_fp16 (reads L3-hot g_Apk image) ----------
__global__ __launch_bounds__(256) void context_kernel(const float* __restrict__ attn,
                                                      float* __restrict__ context) {
    int id = blockIdx.x;              // 32 b x 16 schunk = 512 blocks
    int schunk = id & 15;
    int b = id >> 4;
    int mtile = b * 16 + schunk;      // rows b*2048+schunk*128 .. +127
    int t = threadIdx.x;
    __shared__ float a_s[128];
    if (t < 128) a_s[t] = attn[b * SEQ + schunk * 128 + t];
    __syncthreads();
    int chunk = t >> 1, sh = t & 1;   // chunk = kt*8+cc; sh = row-half (rh)
    int kt = chunk >> 3, cc = chunk & 7;
    const _Float16* src = g_Apk + ((size_t)(mtile * 16 + kt)) * 8192
                        + (size_t)(cc * 2 + sh) * 512;
    const float* as = a_s + sh * 64;
    float acc[8] = {};
#pragma unroll 4
    for (int r = 0; r < 64; ++r) {
        half8v kv = *reinterpret_cast<const half8v*>(src + r * 8);
        float a = as[r];
#pragma unroll
        for (int e = 0; e < 8; ++e) acc[e] += a * (float)kv[e];
    }
    // combine sh=0/1 (adjacent lanes), single atomic writer per d-chunk
#pragma unroll
    for (int e = 0; e < 8; ++e) acc[e] += __shfl_xor(acc[e], 1);
    if (sh == 0) {
        int d = kt * 64 + cc * 8;
#pragma unroll
        for (int e = 0; e < 8; ++e)
            atomicAdd(&context[b * DM + d + e], acc[e]);
    }
}

extern "C" void kernel_launch(void* const* d_in, const int* in_sizes, int n_in,
                              void* d_out, int out_size, void* d_ws, size_t ws_size,
                              hipStream_t stream) {
    const float* query = (const float*)d_in[0];
    const float* keys  = (const float*)d_in[1];
    const float* Wq_w  = (const float*)d_in[2];
    const float* Wq_b  = (const float*)d_in[3];
    const float* Wk_w  = (const float*)d_in[4];
    const float* Wk_b  = (const float*)d_in[5];
    const float* v_w   = (const float*)d_in[6];
    // d_in[7] = v_b: additive constant on all scores -> cancels exactly in softmax.

    float* context = (float*)d_out;              // [32][1024]
    float* attn    = context + BATCH * DM;       // [32][2048]

    hipLaunchKernelGGL(packa_kernel, dim3(8192), dim3(256), 0, stream, keys);
    hipLaunchKernelGGL(packb_kernel, dim3(64), dim3(256), 0, stream, Wk_w);
    hipLaunchKernelGGL(init_kernel, dim3(128), dim3(256), 0, stream, context);
    hipLaunchKernelGGL(qproj_kernel, dim3(DM), dim3(256), 0, stream, query, Wq_w, Wq_b);
    hipLaunchKernelGGL(scores_kernel, dim3((BATCH * SEQ / BM) * (DM / BN)), dim3(256), 0, stream,
                       Wk_b, v_w);
    hipLaunchKernelGGL(softmax_kernel, dim3(BATCH), dim3(256), 0, stream, attn);
    hipLaunchKernelGGL(context_kernel, dim3(512), dim3(256), 0, stream, attn, context);
}

// Round 18
// 257.301 us; speedup vs baseline: 1.2771x; 1.2771x over previous
//
#include <hip/hip_runtime.h>
#include <cstddef>
#include <cstdint>

#define BATCH 32
#define SEQ 2048
#define DM 1024

typedef __attribute__((ext_vector_type(8))) _Float16 half8v;
typedef __attribute__((ext_vector_type(4))) _Float16 half4v;
typedef __attribute__((ext_vector_type(2))) __fp16 fp16x2;   // cvt_pkrtz native type
typedef __attribute__((ext_vector_type(4))) float f32x4;

// Persistent device-global scratch (fully rewritten every launch)
// g_Bpk: Wk_w fp16 in FRAGMENT order [nc 8][sub 8][kt 32][kgrp 4][row 16][e 8] (2 MB).
__device__ _Float16 g_Bpk[8 * 8 * 32 * 4 * 16 * 8];
__device__ float g_q[BATCH * DM];              // q projection (128 KB)
__device__ float g_sp[16][BATCH * SEQ];        // scores partials: slot = nchunk*2 + wn

// tanh(x) = 1 - 2/(e^{2x}+1); saturates to +-1 correctly for |x| large
__device__ __forceinline__ float tanh_fast(float x) {
    float e = __expf(2.0f * x);
    return 1.0f - 2.0f / (e + 1.0f);
}

__device__ __forceinline__ void gload16(const void* g, void* l) {
    __builtin_amdgcn_global_load_lds((__attribute__((address_space(1))) void*)g,
                                     (__attribute__((address_space(3))) void*)l, 16, 0, 0);
}

// ---------------- pack Wk_w -> fp16 fragment-major layout (once, ~4 MB) ----------------
__global__ __launch_bounds__(256) void packb_kernel(const float* __restrict__ Wk_w) {
    int blk = blockIdx.x;              // 0..63 = nc*8 + sub
    int nc = blk >> 3, sub = blk & 7;
    int t = threadIdx.x;
    int row = t & 15, kgrp = (t >> 4) & 3, kt0 = t >> 6;   // kt0: 0..3
    const float* src = Wk_w + (size_t)(nc * 128 + sub * 16 + row) * DM;
    _Float16* dst = g_Bpk + (size_t)blk * 16384;           // block-local [kt][kgrp][row][8]
#pragma unroll
    for (int pass = 0; pass < 8; ++pass) {
        int kt = pass * 4 + kt0;
        float4 w0 = *reinterpret_cast<const float4*>(src + kt * 32 + kgrp * 8);
        float4 w1 = *reinterpret_cast<const float4*>(src + kt * 32 + kgrp * 8 + 4);
        union { _Float16 f[8]; half8v v; } h;
        h.f[0] = (_Float16)w0.x; h.f[1] = (_Float16)w0.y;
        h.f[2] = (_Float16)w0.z; h.f[3] = (_Float16)w0.w;
        h.f[4] = (_Float16)w1.x; h.f[5] = (_Float16)w1.y;
        h.f[6] = (_Float16)w1.z; h.f[7] = (_Float16)w1.w;
        *reinterpret_cast<half8v*>(&dst[(size_t)((kt * 4 + kgrp) * 16 + row) * 8]) = h.v;
    }
}

// ---------------- init: zero context (atomically accumulated) ----------------
__global__ __launch_bounds__(256) void init_kernel(float* __restrict__ context) {
    int idx = blockIdx.x * 256 + threadIdx.x;
    if (idx < BATCH * DM) context[idx] = 0.f;
}

// ---------------- q projection: block per output d; Wq read once total ----------------
__global__ __launch_bounds__(256) void qproj_kernel(const float* __restrict__ query,
                                                    const float* __restrict__ Wq_w,
                                                    const float* __restrict__ Wq_b) {
    int d = blockIdx.x;
    int t = threadIdx.x;
    __shared__ float wrow[DM];
    __shared__ float part[8][32];
    reinterpret_cast<float4*>(wrow)[t] =
        reinterpret_cast<const float4*>(Wq_w + (size_t)d * DM)[t];
    __syncthreads();
    int b = t & 31, seg = t >> 5;
    const float4* qp = reinterpret_cast<const float4*>(query + b * DM + seg * 128);
    const float4* wp = reinterpret_cast<const float4*>(wrow + seg * 128);
    float acc = 0.f;
#pragma unroll
    for (int i = 0; i < 32; ++i) {
        float4 qv = qp[i];
        float4 wv = wp[i];
        acc += qv.x * wv.x + qv.y * wv.y + qv.z * wv.z + qv.w * wv.w;
    }
    part[seg][b] = acc;
    __syncthreads();
    if (t < 32) {
        float s = Wq_b[d];
#pragma unroll
        for (int g = 0; g < 8; ++g) s += part[g][t];
        g_q[t * DM + d] = s;
    }
}

// ---------------- scores: fp16 MFMA GEMM; K-tile=64, 2 sub-steps, 1 barrier/64K ------
#define BM 128
#define BN 128
#define NT2 16   // 16 K-tiles of 64 (= 32 sub-tiles of 32)

// r14-proven config: (256,3), ~33% occupancy, no spill (VGPR 80 + 64 acc AGPR).
__global__ __launch_bounds__(256, 3) void scores_kernel(const float* __restrict__ keys,
                                                        const float* __restrict__ Wk_b,
                                                        const float* __restrict__ v_w) {
    // A in LDS: [dbuf][sub][kc 4][129 rows][8] fp16; kc-plane pad (129) = 4-bank
    // rotate, conflict-free frag reads. 33 KB -> 3 blocks = 99 KB/CU.
    __shared__ _Float16 AhS[2][2][4][BM + 1][8];

    // XCD-aware order: 4096 blocks = 8 XCDs x 512 slots (bijective); nchunk-minor
    // so co-resident blocks share the A-panel (L2 reuse: A read from HBM ~once).
    const unsigned bid = blockIdx.x;
    const unsigned L = (bid & 7u) * 512u + (bid >> 3);
    const int mtile = (int)(L >> 3);       // 0..511
    const int nchunk = (int)(L & 7u);      // 0..7
    const int m0 = mtile * BM;
    const int n0 = nchunk * BN;
    const int b = m0 >> 11;

    const int t = threadIdx.x;
    const int w = t >> 6, l = t & 63;
    const int wm = w >> 1, wn = w & 1;     // 2x2 waves; wave tile 64m x 64n
    const int lr = l & 15, lg = l >> 4;

    // A staging: 8 contiguous 128B row-segments per inst (proven r9-r14 pattern).
    const int akc = (l & 7) >> 1;          // 0..3
    const int aoff = ((l & 7) & 1) * 4;    // 0 or 4
    const float* Ap = keys + (size_t)(m0 + w * 32 + (l >> 3)) * DM + (l & 7) * 4;

    // B-frag base: lane l -> contiguous 16B of frag (kgrp=l>>4, row=l&15).
    const _Float16* Bp = g_Bpk + ((size_t)(nchunk * 8 + wn * 4)) * 16384
                               + (size_t)(l >> 4) * 128 + (size_t)(l & 15) * 8;

    float4 as0[4], as1[4];   // A staging: the two 32-K subs of the NEXT K-tile
    half8v bE[4], bO[4];     // B-frags: bE = sub0, bO = sub1 (named: rule #20)

    f32x4 acc[4][4];
#pragma unroll
    for (int mi = 0; mi < 4; ++mi)
#pragma unroll
        for (int ni = 0; ni < 4; ++ni)
#pragma unroll
            for (int c = 0; c < 4; ++c) acc[mi][ni][c] = 0.f;

    // kt = K-tile index (64-K units); ks = sub-tile index (32-K units)
#define LOAD_A2(kt)                                                              \
    {                                                                            \
        _Pragma("unroll") for (int j = 0; j < 4; ++j)                            \
            as0[j] = *reinterpret_cast<const float4*>(                           \
                Ap + (size_t)j * 8 * DM + (kt) * 64);                            \
        _Pragma("unroll") for (int j = 0; j < 4; ++j)                            \
            as1[j] = *reinterpret_cast<const float4*>(                           \
                Ap + (size_t)j * 8 * DM + (kt) * 64 + 32);                       \
    }
#define LOAD_BF(ks, dst)                                                         \
    {                                                                            \
        _Pragma("unroll") for (int ni = 0; ni < 4; ++ni)                         \
            dst[ni] = *reinterpret_cast<const half8v*>(                          \
                Bp + (size_t)ni * 16384 + (size_t)(ks) * 512);                   \
    }
    // pkrtz staging: 2 VALU per float4 (r13/r15-proven; absmax unchanged 4.88e-4)
#define STAGE_ONE(bufi, sub, areg)                                               \
    {                                                                            \
        _Pragma("unroll") for (int j = 0; j < 4; ++j) {                          \
            const float* fa = reinterpret_cast<const float*>(&areg[j]);          \
            union { fp16x2 h2[2]; half4v v; } u;                                 \
            u.h2[0] = __builtin_amdgcn_cvt_pkrtz(fa[0], fa[1]);                  \
            u.h2[1] = __builtin_amdgcn_cvt_pkrtz(fa[2], fa[3]);                  \
            *reinterpret_cast<half4v*>(                                          \
                &AhS[bufi][sub][akc][w * 32 + j * 8 + (l >> 3)][aoff]) = u.v;    \
        }                                                                        \
    }
#define COMPUTE_S(bufi, sub, breg)                                               \
    {                                                                            \
        __builtin_amdgcn_s_setprio(1);                                           \
        _Pragma("unroll") for (int mi = 0; mi < 4; ++mi) {                       \
            half8v ahv = *reinterpret_cast<const half8v*>(                       \
                &AhS[bufi][sub][lg][wm * 64 + mi * 16 + lr][0]);                 \
            _Pragma("unroll") for (int ni = 0; ni < 4; ++ni)                     \
                acc[mi][ni] = __builtin_amdgcn_mfma_f32_16x16x32_f16(            \
                    ahv, breg[ni], acc[mi][ni], 0, 0, 0);                        \
        }                                                                        \
        __builtin_amdgcn_s_setprio(0);                                          \
    }
    // LDS hazards only need lgkmcnt; global loads ride the barrier (compiler
    // scoreboard inserts counted vmcnt before each register use).
#define SYNC()                                                                   \
    asm volatile("s_waitcnt lgkmcnt(0)" ::: "memory");                           \
    __builtin_amdgcn_s_barrier();                                                \
    asm volatile("" ::: "memory");

    // ---- prologue: K-tile 0 -> buf0; B(sub0=0) -> bE ----
    LOAD_A2(0);
    LOAD_BF(0, bE);
    STAGE_ONE(0, 0, as0);       // scoreboard waits as regs
    STAGE_ONE(0, 1, as1);
    SYNC()

    // ---- main loop: one barrier per 64-K tile; 32 MFMA/wave per interval ----
    for (int tt = 0; tt < NT2; ++tt) {
        const int cb = tt & 1;
        LOAD_BF(2 * tt + 1, bO);
        if (tt + 1 < NT2) LOAD_A2(tt + 1);
        COMPUTE_S(cb, 0, bE);
        COMPUTE_S(cb, 1, bO);
        if (tt + 1 < NT2) {
            STAGE_ONE(cb ^ 1, 0, as0);
            STAGE_ONE(cb ^ 1, 1, as1);
            LOAD_BF(2 * tt + 2, bE);
        }
        SYNC()
    }

    // epilogue: tanh * v_w, reduce over this wave's 64 n-cols.
    // Slot = nchunk*2 + wn: exactly ONE writer per (slot,row) -> deterministic.
    float qb[4], vw[4];
#pragma unroll
    for (int ni = 0; ni < 4; ++ni) {
        int n = n0 + wn * 64 + ni * 16 + lr;
        qb[ni] = g_q[b * DM + n] + Wk_b[n];
        vw[ni] = v_w[n];
    }
#pragma unroll
    for (int mi = 0; mi < 4; ++mi) {
#pragma unroll
        for (int rg = 0; rg < 4; ++rg) {
            float p = 0.f;
#pragma unroll
            for (int ni = 0; ni < 4; ++ni) {
                float val = acc[mi][ni][rg] + qb[ni];
                p += tanh_fast(val) * vw[ni];
            }
#pragma unroll
            for (int off = 8; off >= 1; off >>= 1) p += __shfl_xor(p, off, 16);
            if (lr == 0)
                g_sp[nchunk * 2 + wn][m0 + wm * 64 + mi * 16 + lg * 4 + rg] = p;
        }
    }
#undef LOAD_A2
#undef LOAD_BF
#undef STAGE_ONE
#undef COMPUTE_S
#undef SYNC
}

// ---------------- softmax over S per batch row (sums the 16 partial slots) --------
__global__ __launch_bounds__(256) void softmax_kernel(float* __restrict__ attn) {
    int b = blockIdx.x;
    int tid = threadIdx.x;
    __shared__ float redm[4];
    __shared__ float reds[4];
    float v[8];
    float mx = -1e30f;
#pragma unroll
    for (int i = 0; i < 8; ++i) {
        int idx = b * SEQ + i * 256 + tid;
        float s = 0.f;
#pragma unroll
        for (int pslot = 0; pslot < 16; ++pslot) s += g_sp[pslot][idx];
        v[i] = s;
        mx = fmaxf(mx, v[i]);
    }
#pragma unroll
    for (int off = 32; off >= 1; off >>= 1) mx = fmaxf(mx, __shfl_xor(mx, off));
    int wid = tid >> 6;
    if ((tid & 63) == 0) redm[wid] = mx;
    __syncthreads();
    mx = fmaxf(fmaxf(redm[0], redm[1]), fmaxf(redm[2], redm[3]));
    float sum = 0.f;
#pragma unroll
    for (int i = 0; i < 8; ++i) {
        v[i] = expf(v[i] - mx);
        sum += v[i];
    }
#pragma unroll
    for (int off = 32; off >= 1; off >>= 1) sum += __shfl_xor(sum, off);
    if ((tid & 63) == 0) reds[wid] = sum;
    __syncthreads();
    sum = reds[0] + reds[1] + reds[2] + reds[3];
    float inv = 1.f / sum;
#pragma unroll
    for (int i = 0; i < 8; ++i) attn[b * SEQ + i * 256 + tid] = v[i] * inv;
}

// ---------------- context = attn @ keys (coalesced float4 rows; keys is L3-hot) ------
__global__ __launch_bounds__(256) void context_kernel(const float* __restrict__ keys,
                                                      const float* __restrict__ attn,
                                                      float* __restrict__ context) {
    int id = blockIdx.x;              // 32 b x 16 schunk = 512 blocks
    int schunk = id & 15;
    int b = id >> 4;
    int tid = threadIdx.x;
    __shared__ float a_s[128];
    if (tid < 128) a_s[tid] = attn[b * SEQ + schunk * 128 + tid];
    __syncthreads();
    const float4* kp =
        reinterpret_cast<const float4*>(keys + ((size_t)b * SEQ + schunk * 128) * DM) + tid;
    float4 acc = {0.f, 0.f, 0.f, 0.f};
#pragma unroll 4
    for (int s = 0; s < 128; ++s) {
        float4 kv = kp[(size_t)s * (DM / 4)];
        float a = a_s[s];
        acc.x += a * kv.x; acc.y += a * kv.y; acc.z += a * kv.z; acc.w += a * kv.w;
    }
    atomicAdd(&context[b * DM + tid * 4 + 0], acc.x);
    atomicAdd(&context[b * DM + tid * 4 + 1], acc.y);
    atomicAdd(&context[b * DM + tid * 4 + 2], acc.z);
    atomicAdd(&context[b * DM + tid * 4 + 3], acc.w);
}

extern "C" void kernel_launch(void* const* d_in, const int* in_sizes, int n_in,
                              void* d_out, int out_size, void* d_ws, size_t ws_size,
                              hipStream_t stream) {
    const float* query = (const float*)d_in[0];
    const float* keys  = (const float*)d_in[1];
    const float* Wq_w  = (const float*)d_in[2];
    const float* Wq_b  = (const float*)d_in[3];
    const float* Wk_w  = (const float*)d_in[4];
    const float* Wk_b  = (const float*)d_in[5];
    const float* v_w   = (const float*)d_in[6];
    // d_in[7] = v_b: additive constant on all scores -> cancels exactly in softmax.

    float* context = (float*)d_out;              // [32][1024]
    float* attn    = context + BATCH * DM;       // [32][2048]

    hipLaunchKernelGGL(packb_kernel, dim3(64), dim3(256), 0, stream, Wk_w);
    hipLaunchKernelGGL(init_kernel, dim3(128), dim3(256), 0, stream, context);
    hipLaunchKernelGGL(qproj_kernel, dim3(DM), dim3(256), 0, stream, query, Wq_w, Wq_b);
    hipLaunchKernelGGL(scores_kernel, dim3((BATCH * SEQ / BM) * (DM / BN)), dim3(256), 0, stream,
                       keys, Wk_b, v_w);
    hipLaunchKernelGGL(softmax_kernel, dim3(BATCH), dim3(256), 0, stream, attn);
    hipLaunchKernelGGL(context_kernel, dim3(512), dim3(256), 0, stream, keys, attn, context);
}

// Round 19
// 236.924 us; speedup vs baseline: 1.3869x; 1.0860x over previous
//
#include <hip/hip_runtime.h>
#include <cstddef>
#include <cstdint>

#define BATCH 32
#define SEQ 2048
#define DM 1024

typedef __attribute__((ext_vector_type(8))) _Float16 half8v;
typedef __attribute__((ext_vector_type(4))) _Float16 half4v;
typedef __attribute__((ext_vector_type(2))) __fp16 fp16x2;   // cvt_pkrtz native type
typedef __attribute__((ext_vector_type(4))) float f32x4;

// Persistent device-global scratch (fully rewritten every launch)
// g_Bpk: Wk_w fp16 in FRAGMENT order [nc 8][sub 8][kt 32][kgrp 4][row 16][e 8] (2 MB).
__device__ _Float16 g_Bpk[8 * 8 * 32 * 4 * 16 * 8];
__device__ float g_q[BATCH * DM];              // q projection (128 KB)
__device__ float g_sp[8][BATCH * SEQ];         // scores partials: slot = nchunk*2 + wn

// tanh(x) = 1 - 2/(e^{2x}+1); saturates to +-1 correctly for |x| large
__device__ __forceinline__ float tanh_fast(float x) {
    float e = __expf(2.0f * x);
    return 1.0f - 2.0f / (e + 1.0f);
}

// ---------------- pack Wk_w -> fp16 fragment-major layout (once, ~4 MB) ----------------
__global__ __launch_bounds__(256) void packb_kernel(const float* __restrict__ Wk_w) {
    int blk = blockIdx.x;              // 0..63 = nc*8 + sub
    int nc = blk >> 3, sub = blk & 7;
    int t = threadIdx.x;
    int row = t & 15, kgrp = (t >> 4) & 3, kt0 = t >> 6;   // kt0: 0..3
    const float* src = Wk_w + (size_t)(nc * 128 + sub * 16 + row) * DM;
    _Float16* dst = g_Bpk + (size_t)blk * 16384;           // block-local [kt][kgrp][row][8]
#pragma unroll
    for (int pass = 0; pass < 8; ++pass) {
        int kt = pass * 4 + kt0;
        float4 w0 = *reinterpret_cast<const float4*>(src + kt * 32 + kgrp * 8);
        float4 w1 = *reinterpret_cast<const float4*>(src + kt * 32 + kgrp * 8 + 4);
        union { _Float16 f[8]; half8v v; } h;
        h.f[0] = (_Float16)w0.x; h.f[1] = (_Float16)w0.y;
        h.f[2] = (_Float16)w0.z; h.f[3] = (_Float16)w0.w;
        h.f[4] = (_Float16)w1.x; h.f[5] = (_Float16)w1.y;
        h.f[6] = (_Float16)w1.z; h.f[7] = (_Float16)w1.w;
        *reinterpret_cast<half8v*>(&dst[(size_t)((kt * 4 + kgrp) * 16 + row) * 8]) = h.v;
    }
}

// ---------------- init: zero context (atomically accumulated) ----------------
__global__ __launch_bounds__(256) void init_kernel(float* __restrict__ context) {
    int idx = blockIdx.x * 256 + threadIdx.x;
    if (idx < BATCH * DM) context[idx] = 0.f;
}

// ---------------- q projection: block per output d; Wq read once total ----------------
__global__ __launch_bounds__(256) void qproj_kernel(const float* __restrict__ query,
                                                    const float* __restrict__ Wq_w,
                                                    const float* __restrict__ Wq_b) {
    int d = blockIdx.x;
    int t = threadIdx.x;
    __shared__ float wrow[DM];
    __shared__ float part[8][32];
    reinterpret_cast<float4*>(wrow)[t] =
        reinterpret_cast<const float4*>(Wq_w + (size_t)d * DM)[t];
    __syncthreads();
    int b = t & 31, seg = t >> 5;
    const float4* qp = reinterpret_cast<const float4*>(query + b * DM + seg * 128);
    const float4* wp = reinterpret_cast<const float4*>(wrow + seg * 128);
    float acc = 0.f;
#pragma unroll
    for (int i = 0; i < 32; ++i) {
        float4 qv = qp[i];
        float4 wv = wp[i];
        acc += qv.x * wv.x + qv.y * wv.y + qv.z * wv.z + qv.w * wv.w;
    }
    part[seg][b] = acc;
    __syncthreads();
    if (t < 32) {
        float s = Wq_b[d];
#pragma unroll
        for (int g = 0; g < 8; ++g) s += part[g][t];
        g_q[t * DM + d] = s;
    }
}

// ---------------- scores: fp16 MFMA GEMM; BN=256, K-tile=64, 1 barrier/64K ------
#define BM 128
#define BN 256
#define NT2 16   // 16 K-tiles of 64 (= 32 sub-tiles of 32)

// Regs: acc 128 + A-stage 32 + B-frags 64 + misc ~25 ~= 249 <= 256 @ 2 waves/SIMD.
// WRITE_SIZE is the spill tripwire (r7 lesson).
__global__ __launch_bounds__(256, 2) void scores_kernel(const float* __restrict__ keys,
                                                        const float* __restrict__ Wk_b,
                                                        const float* __restrict__ v_w) {
    // A in LDS: [dbuf][sub][kc 4][129 rows][8] fp16; kc-plane pad (129) = 4-bank
    // rotate, conflict-free frag reads. 33 KB.
    __shared__ _Float16 AhS[2][2][4][BM + 1][8];

    // XCD-aware order: 2048 blocks = 8 XCDs x 256 slots (bijective); nchunk-minor
    // so the 4 blocks sharing an A-panel are co-resident on one XCD.
    const unsigned bid = blockIdx.x;
    const unsigned L = (bid & 7u) * 256u + (bid >> 3);
    const int mtile = (int)(L >> 2);       // 0..511
    const int nchunk = (int)(L & 3u);      // 0..3
    const int m0 = mtile * BM;
    const int b = m0 >> 11;

    const int t = threadIdx.x;
    const int w = t >> 6, l = t & 63;
    const int wm = w >> 1, wn = w & 1;     // 2x2 waves; wave tile 64m x 128n
    const int lr = l & 15, lg = l >> 4;

    // A staging: 8 contiguous 128B row-segments per inst (proven r9-r18 pattern).
    const int akc = (l & 7) >> 1;          // 0..3
    const int aoff = ((l & 7) & 1) * 4;    // 0 or 4
    const float* Ap = keys + (size_t)(m0 + w * 32 + (l >> 3)) * DM + (l & 7) * 4;

    // Wave's 128-col strip = old-nc unit (nchunk*2 + wn) of the g_Bpk layout.
    // B-frag base: lane l -> contiguous 16B of frag (kgrp=l>>4, row=l&15).
    const int oldnc = nchunk * 2 + wn;
    const _Float16* Bp = g_Bpk + (size_t)oldnc * 8 * 16384
                               + (size_t)(l >> 4) * 128 + (size_t)(l & 15) * 8;

    float4 as0[4], as1[4];   // A staging: the two 32-K subs of the NEXT K-tile
    half8v bE[8], bO[8];     // B-frags: bE = sub0, bO = sub1 (named: rule #20)

    f32x4 acc[4][8];
#pragma unroll
    for (int mi = 0; mi < 4; ++mi)
#pragma unroll
        for (int ni = 0; ni < 8; ++ni)
#pragma unroll
            for (int c = 0; c < 4; ++c) acc[mi][ni][c] = 0.f;

    // kt = K-tile index (64-K units); ks = sub-tile index (32-K units)
#define LOAD_A2(kt)                                                              \
    {                                                                            \
        _Pragma("unroll") for (int j = 0; j < 4; ++j)                            \
            as0[j] = *reinterpret_cast<const float4*>(                           \
                Ap + (size_t)j * 8 * DM + (kt) * 64);                            \
        _Pragma("unroll") for (int j = 0; j < 4; ++j)                            \
            as1[j] = *reinterpret_cast<const float4*>(                           \
                Ap + (size_t)j * 8 * DM + (kt) * 64 + 32);                       \
    }
#define LOAD_BF(ks, dst)                                                         \
    {                                                                            \
        _Pragma("unroll") for (int ni = 0; ni < 8; ++ni)                         \
            dst[ni] = *reinterpret_cast<const half8v*>(                          \
                Bp + (size_t)ni * 16384 + (size_t)(ks) * 512);                   \
    }
    // pkrtz staging: 2 VALU per float4
#define STAGE_ONE(bufi, sub, areg)                                               \
    {                                                                            \
        _Pragma("unroll") for (int j = 0; j < 4; ++j) {                          \
            const float* fa = reinterpret_cast<const float*>(&areg[j]);          \
            union { fp16x2 h2[2]; half4v v; } u;                                 \
            u.h2[0] = __builtin_amdgcn_cvt_pkrtz(fa[0], fa[1]);                  \
            u.h2[1] = __builtin_amdgcn_cvt_pkrtz(fa[2], fa[3]);                  \
            *reinterpret_cast<half4v*>(                                          \
                &AhS[bufi][sub][akc][w * 32 + j * 8 + (l >> 3)][aoff]) = u.v;    \
        }                                                                        \
    }
#define COMPUTE_S(bufi, sub, breg)                                               \
    {                                                                            \
        __builtin_amdgcn_s_setprio(1);                                           \
        _Pragma("unroll") for (int mi = 0; mi < 4; ++mi) {                       \
            half8v ahv = *reinterpret_cast<const half8v*>(                       \
                &AhS[bufi][sub][lg][wm * 64 + mi * 16 + lr][0]);                 \
            _Pragma("unroll") for (int ni = 0; ni < 8; ++ni)                     \
                acc[mi][ni] = __builtin_amdgcn_mfma_f32_16x16x32_f16(            \
                    ahv, breg[ni], acc[mi][ni], 0, 0, 0);                        \
        }                                                                        \
        __builtin_amdgcn_s_setprio(0);                                          \
    }
    // LDS hazards only need lgkmcnt; global loads ride the barrier (compiler
    // scoreboard inserts counted vmcnt before each register use).
#define SYNC()                                                                   \
    asm volatile("s_waitcnt lgkmcnt(0)" ::: "memory");                           \
    __builtin_amdgcn_s_barrier();                                                \
    asm volatile("" ::: "memory");

    // ---- prologue: K-tile 0 -> buf0; B(sub0=0) -> bE ----
    LOAD_A2(0);
    LOAD_BF(0, bE);
    STAGE_ONE(0, 0, as0);       // scoreboard waits as regs
    STAGE_ONE(0, 1, as1);
    SYNC()

    // ---- main loop: one barrier per 64-K tile; 64 MFMA/wave per interval ----
    for (int tt = 0; tt < NT2; ++tt) {
        const int cb = tt & 1;
        LOAD_BF(2 * tt + 1, bO);
        if (tt + 1 < NT2) LOAD_A2(tt + 1);
        COMPUTE_S(cb, 0, bE);
        COMPUTE_S(cb, 1, bO);
        if (tt + 1 < NT2) {
            STAGE_ONE(cb ^ 1, 0, as0);
            STAGE_ONE(cb ^ 1, 1, as1);
            LOAD_BF(2 * tt + 2, bE);
        }
        SYNC()
    }

    // epilogue: tanh * v_w, reduce over this wave's 128 n-cols.
    // Slot = nchunk*2 + wn = oldnc: exactly ONE writer per (slot,row).
    float qb[8], vw[8];
#pragma unroll
    for (int ni = 0; ni < 8; ++ni) {
        int n = oldnc * 128 + ni * 16 + lr;
        qb[ni] = g_q[b * DM + n] + Wk_b[n];
        vw[ni] = v_w[n];
    }
#pragma unroll
    for (int mi = 0; mi < 4; ++mi) {
#pragma unroll
        for (int rg = 0; rg < 4; ++rg) {
            float p = 0.f;
#pragma unroll
            for (int ni = 0; ni < 8; ++ni) {
                float val = acc[mi][ni][rg] + qb[ni];
                p += tanh_fast(val) * vw[ni];
            }
#pragma unroll
            for (int off = 8; off >= 1; off >>= 1) p += __shfl_xor(p, off, 16);
            if (lr == 0)
                g_sp[oldnc][m0 + wm * 64 + mi * 16 + lg * 4 + rg] = p;
        }
    }
#undef LOAD_A2
#undef LOAD_BF
#undef STAGE_ONE
#undef COMPUTE_S
#undef SYNC
}

// ---------------- softmax over S per batch row (sums the 8 partial slots) --------
__global__ __launch_bounds__(256) void softmax_kernel(float* __restrict__ attn) {
    int b = blockIdx.x;
    int tid = threadIdx.x;
    __shared__ float redm[4];
    __shared__ float reds[4];
    float v[8];
    float mx = -1e30f;
#pragma unroll
    for (int i = 0; i < 8; ++i) {
        int idx = b * SEQ + i * 256 + tid;
        float s = 0.f;
#pragma unroll
        for (int pslot = 0; pslot < 8; ++pslot) s += g_sp[pslot][idx];
        v[i] = s;
        mx = fmaxf(mx, v[i]);
    }
#pragma unroll
    for (int off = 32; off >= 1; off >>= 1) mx = fmaxf(mx, __shfl_xor(mx, off));
    int wid = tid >> 6;
    if ((tid & 63) == 0) redm[wid] = mx;
    __syncthreads();
    mx = fmaxf(fmaxf(redm[0], redm[1]), fmaxf(redm[2], redm[3]));
    float sum = 0.f;
#pragma unroll
    for (int i = 0; i < 8; ++i) {
        v[i] = expf(v[i] - mx);
        sum += v[i];
    }
#pragma unroll
    for (int off = 32; off >= 1; off >>= 1) sum += __shfl_xor(sum, off);
    if ((tid & 63) == 0) reds[wid] = sum;
    __syncthreads();
    sum = reds[0] + reds[1] + reds[2] + reds[3];
    float inv = 1.f / sum;
#pragma unroll
    for (int i = 0; i < 8; ++i) attn[b * SEQ + i * 256 + tid] = v[i] * inv;
}

// ---------------- context = attn @ keys (coalesced float4 rows; keys is L3-hot) ------
__global__ __launch_bounds__(256) void context_kernel(const float* __restrict__ keys,
                                                      const float* __restrict__ attn,
                                                      float* __restrict__ context) {
    int id = blockIdx.x;              // 32 b x 16 schunk = 512 blocks
    int schunk = id & 15;
    int b = id >> 4;
    int tid = threadIdx.x;
    __shared__ float a_s[128];
    if (tid < 128) a_s[tid] = attn[b * SEQ + schunk * 128 + tid];
    __syncthreads();
    const float4* kp =
        reinterpret_cast<const float4*>(keys + ((size_t)b * SEQ + schunk * 128) * DM) + tid;
    float4 acc = {0.f, 0.f, 0.f, 0.f};
#pragma unroll 4
    for (int s = 0; s < 128; ++s) {
        float4 kv = kp[(size_t)s * (DM / 4)];
        float a = a_s[s];
        acc.x += a * kv.x; acc.y += a * kv.y; acc.z += a * kv.z; acc.w += a * kv.w;
    }
    atomicAdd(&context[b * DM + tid * 4 + 0], acc.x);
    atomicAdd(&context[b * DM + tid * 4 + 1], acc.y);
    atomicAdd(&context[b * DM + tid * 4 + 2], acc.z);
    atomicAdd(&context[b * DM + tid * 4 + 3], acc.w);
}

extern "C" void kernel_launch(void* const* d_in, const int* in_sizes, int n_in,
                              void* d_out, int out_size, void* d_ws, size_t ws_size,
                              hipStream_t stream) {
    const float* query = (const float*)d_in[0];
    const float* keys  = (const float*)d_in[1];
    const float* Wq_w  = (const float*)d_in[2];
    const float* Wq_b  = (const float*)d_in[3];
    const float* Wk_w  = (const float*)d_in[4];
    const float* Wk_b  = (const float*)d_in[5];
    const float* v_w   = (const float*)d_in[6];
    // d_in[7] = v_b: additive constant on all scores -> cancels exactly in softmax.

    float* context = (float*)d_out;              // [32][1024]
    float* attn    = context + BATCH * DM;       // [32][2048]

    hipLaunchKernelGGL(packb_kernel, dim3(64), dim3(256), 0, stream, Wk_w);
    hipLaunchKernelGGL(init_kernel, dim3(128), dim3(256), 0, stream, context);
    hipLaunchKernelGGL(qproj_kernel, dim3(DM), dim3(256), 0, stream, query, Wq_w, Wq_b);
    hipLaunchKernelGGL(scores_kernel, dim3((BATCH * SEQ / BM) * (DM / BN)), dim3(256), 0, stream,
                       keys, Wk_b, v_w);
    hipLaunchKernelGGL(softmax_kernel, dim3(BATCH), dim3(256), 0, stream, attn);
    hipLaunchKernelGGL(context_kernel, dim3(512), dim3(256), 0, stream, keys, attn, context);
}